// Round 1
// baseline (907.058 us; speedup 1.0000x reference)
//
#include <hip/hip_runtime.h>
#include <hip/hip_bf16.h>

// Capsule routing: B=64, R=2048, C=32, O=32, I=32, 3 iterations.
// u_hat never materialized to HBM: recomputed per pass from (bf16) W via MFMA.

#define B_  64
#define R_  2048
#define CI  32     // in channels (K)
#define NC  32     // num capsules
#define OC  32     // out channels
#define NCO 1024   // NC*OC, the N dimension
#define RCHUNK 8
#define NCHUNKS (R_ / RCHUNK)   // 256

typedef __attribute__((ext_vector_type(8))) short bf16x8;
typedef __attribute__((ext_vector_type(4))) float f32x4;

static constexpr long WN = (long)R_ * NC * OC * CI;  // 67,108,864
static constexpr long XN = (long)B_ * R_ * CI;       // 4,194,304

__device__ __forceinline__ unsigned short rne_bf16(float f) {
  unsigned int u = __builtin_bit_cast(unsigned int, f);
  u += 0x7fffu + ((u >> 16) & 1u);   // round-to-nearest-even (finite inputs)
  return (unsigned short)(u >> 16);
}

__device__ __forceinline__ bf16x8 pack8(float4 a, float4 b) {
  bf16x8 r;
  r[0] = (short)rne_bf16(a.x); r[1] = (short)rne_bf16(a.y);
  r[2] = (short)rne_bf16(a.z); r[3] = (short)rne_bf16(a.w);
  r[4] = (short)rne_bf16(b.x); r[5] = (short)rne_bf16(b.y);
  r[6] = (short)rne_bf16(b.z); r[7] = (short)rne_bf16(b.w);
  return r;
}

// f32 -> bf16 conversion, vectorized (n4 = n/4)
__global__ __launch_bounds__(256) void cvt_kernel(const float* __restrict__ src,
                                                  unsigned short* __restrict__ dst,
                                                  int n4) {
  int i = blockIdx.x * blockDim.x + threadIdx.x;
  int stride = gridDim.x * blockDim.x;
  const float4* s4 = (const float4*)src;
  ushort4* d4 = (ushort4*)dst;
  for (; i < n4; i += stride) {
    float4 f = s4[i];
    ushort4 u;
    u.x = rne_bf16(f.x); u.y = rne_bf16(f.y);
    u.z = rne_bf16(f.z); u.w = rne_bf16(f.w);
    d4[i] = u;
  }
}

// s-pass: s[b,c,o] += sum_r c[r,c] * (W[r,c,o,:] . x[b,r,:])
// grid = (NCHUNKS, 4 c-groups), block = 256 (4 waves, wave mw = M-tile)
template<bool FAST>
__global__ __launch_bounds__(256) void s_pass_kernel(
    const float* __restrict__ x, const float* __restrict__ W,
    const unsigned short* __restrict__ xb, const unsigned short* __restrict__ Wb,
    const float* __restrict__ cmat,   // [C][R]
    float* __restrict__ s,            // [B][NCO]
    int uniform) {
  const int tid  = threadIdx.x;
  const int lane = tid & 63;
  const int mw   = tid >> 6;          // M-tile (rows 16*mw..)
  const int g    = blockIdx.y;        // c-group: capsules 8g..8g+7, cols 256g..
  const int r0   = blockIdx.x * RCHUNK;
  const int l15  = lane & 15;
  const int q    = lane >> 4;
  const int k0   = q * 8;
  const int bA   = mw * 16 + l15;     // A-operand row (m = lane&15)

  f32x4 acc[16];
#pragma unroll
  for (int t = 0; t < 16; ++t) acc[t] = (f32x4){0.f, 0.f, 0.f, 0.f};
  const f32x4 zero4 = (f32x4){0.f, 0.f, 0.f, 0.f};

  for (int j = 0; j < RCHUNK; ++j) {
    const int r = r0 + j;
    bf16x8 af;
    if (FAST) {
      af = *(const bf16x8*)(xb + ((bA * R_ + r) * CI + k0));
    } else {
      const float* xp = x + ((bA * R_ + r) * CI + k0);
      af = pack8(*(const float4*)xp, *(const float4*)(xp + 4));
    }
    float cv[8];
#pragma unroll
    for (int cc = 0; cc < 8; ++cc)
      cv[cc] = uniform ? (1.0f / 2048.0f) : cmat[(g * 8 + cc) * R_ + r];
#pragma unroll
    for (int t = 0; t < 16; ++t) {
      const int nrow = (g * 16 + t) * 16 + l15;   // B-operand row (n = lane&15)
      bf16x8 bfr;
      if (FAST) {
        bfr = *(const bf16x8*)(Wb + (r * NCO + nrow) * CI + k0);
      } else {
        const float* wp = W + (r * NCO + nrow) * CI + k0;
        bfr = pack8(*(const float4*)wp, *(const float4*)(wp + 4));
      }
      f32x4 u = __builtin_amdgcn_mfma_f32_16x16x32_bf16(af, bfr, zero4, 0, 0, 0);
      const float c = cv[t >> 1];   // capsule constant within a 16-wide n-tile (O=32)
      acc[t] += c * u;
    }
  }
  // C/D layout: row(m) = (lane>>4)*4 + reg, col(n) = lane&15
#pragma unroll
  for (int t = 0; t < 16; ++t) {
    const int n = (g * 16 + t) * 16 + l15;
#pragma unroll
    for (int rr = 0; rr < 4; ++rr) {
      const int b = mw * 16 + q * 4 + rr;
      atomicAdd(s + (b * NCO + n), acc[t][rr]);
    }
  }
}

// a-pass: bb[c][r] += (1/64) * sum_{b,o} u_hat[b,r,c,o] * v[b,c,o]
template<bool FAST>
__global__ __launch_bounds__(256) void a_pass_kernel(
    const float* __restrict__ x, const float* __restrict__ W,
    const unsigned short* __restrict__ xb, const unsigned short* __restrict__ Wb,
    const float* __restrict__ v,    // [B][NCO]
    float* __restrict__ bb) {       // [C][R]
  const int tid  = threadIdx.x;
  const int lane = tid & 63;
  const int mw   = tid >> 6;
  const int g    = blockIdx.y;
  const int r0   = blockIdx.x * RCHUNK;
  const int l15  = lane & 15;
  const int q    = lane >> 4;
  const int k0   = q * 8;
  const int bA   = mw * 16 + l15;

  // preload v in exact MFMA C-layout
  float vreg[16][4];
#pragma unroll
  for (int t = 0; t < 16; ++t) {
    const int n = (g * 16 + t) * 16 + l15;
#pragma unroll
    for (int rr = 0; rr < 4; ++rr)
      vreg[t][rr] = v[(mw * 16 + q * 4 + rr) * NCO + n];
  }
  const f32x4 zero4 = (f32x4){0.f, 0.f, 0.f, 0.f};

  for (int j = 0; j < RCHUNK; ++j) {
    const int r = r0 + j;
    bf16x8 af;
    if (FAST) {
      af = *(const bf16x8*)(xb + ((bA * R_ + r) * CI + k0));
    } else {
      const float* xp = x + ((bA * R_ + r) * CI + k0);
      af = pack8(*(const float4*)xp, *(const float4*)(xp + 4));
    }
    float dotc[8];
#pragma unroll
    for (int cc = 0; cc < 8; ++cc) dotc[cc] = 0.f;
#pragma unroll
    for (int t = 0; t < 16; ++t) {
      const int nrow = (g * 16 + t) * 16 + l15;
      bf16x8 bfr;
      if (FAST) {
        bfr = *(const bf16x8*)(Wb + (r * NCO + nrow) * CI + k0);
      } else {
        const float* wp = W + (r * NCO + nrow) * CI + k0;
        bfr = pack8(*(const float4*)wp, *(const float4*)(wp + 4));
      }
      f32x4 u = __builtin_amdgcn_mfma_f32_16x16x32_bf16(af, bfr, zero4, 0, 0, 0);
      dotc[t >> 1] += u[0] * vreg[t][0] + u[1] * vreg[t][1] +
                      u[2] * vreg[t][2] + u[3] * vreg[t][3];
    }
    // reduce each capsule partial across the wave's 64 lanes
#pragma unroll
    for (int cc = 0; cc < 8; ++cc) {
#pragma unroll
      for (int m = 1; m < 64; m <<= 1) dotc[cc] += __shfl_xor(dotc[cc], m);
    }
    if (lane == 0) {
#pragma unroll
      for (int cc = 0; cc < 8; ++cc)
        atomicAdd(bb + ((g * 8 + cc) * R_ + r), dotc[cc] * (1.0f / 64.0f));
    }
  }
}

// softmax over routes for each capsule: cmat[c][r] = softmax_r(bb[c][r])
__global__ __launch_bounds__(256) void softmax_kernel(const float* __restrict__ bb,
                                                      float* __restrict__ cmat) {
  const int c = blockIdx.x;
  const int tid = threadIdx.x;
  __shared__ float red[8];
  float m = -1e30f;
  for (int r = tid; r < R_; r += 256) m = fmaxf(m, bb[c * R_ + r]);
#pragma unroll
  for (int s = 1; s < 64; s <<= 1) m = fmaxf(m, __shfl_xor(m, s));
  if ((tid & 63) == 0) red[tid >> 6] = m;
  __syncthreads();
  m = fmaxf(fmaxf(red[0], red[1]), fmaxf(red[2], red[3]));
  float sum = 0.f;
  for (int r = tid; r < R_; r += 256) sum += __expf(bb[c * R_ + r] - m);
#pragma unroll
  for (int s = 1; s < 64; s <<= 1) sum += __shfl_xor(sum, s);
  if ((tid & 63) == 0) red[4 + (tid >> 6)] = sum;
  __syncthreads();
  sum = red[4] + red[5] + red[6] + red[7];
  const float inv = 1.0f / sum;
  for (int r = tid; r < R_; r += 256)
    cmat[c * R_ + r] = __expf(bb[c * R_ + r] - m) * inv;
}

// squash, exact reference formula: sq*s / ((1+sq)*sqrt(sq))
__global__ __launch_bounds__(256) void squash_kernel(const float* __restrict__ s,
                                                     float* __restrict__ o) {
  const int i = blockIdx.x * blockDim.x + threadIdx.x;
  const float sv = s[i];
  const float sq = sv * sv;
  o[i] = sq * sv / ((1.0f + sq) * sqrtf(sq));
}

extern "C" void kernel_launch(void* const* d_in, const int* in_sizes, int n_in,
                              void* d_out, int out_size, void* d_ws, size_t ws_size,
                              hipStream_t stream) {
  const float* x = (const float*)d_in[0];   // [64, 2048, 32]
  const float* W = (const float*)d_in[1];   // [2048, 32, 32, 32]
  float* out = (float*)d_out;               // [64, 32, 32, 1]

  char* ws = (char*)d_ws;
  float* s    = (float*)(ws);                         // 256 KB
  float* bb   = (float*)(ws + (1 << 18));             // 256 KB
  float* cmat = (float*)(ws + 2 * (size_t)(1 << 18)); // 256 KB
  float* vbuf = (float*)(ws + 3 * (size_t)(1 << 18)); // 256 KB
  unsigned short* Wb = (unsigned short*)(ws + (1 << 20));
  unsigned short* xb = (unsigned short*)(ws + (1 << 20) + (size_t)WN * 2);
  const size_t need_fast = (size_t)(1 << 20) + (size_t)WN * 2 + (size_t)XN * 2;
  const bool fast = ws_size >= need_fast;

  if (fast) {
    cvt_kernel<<<4096, 256, 0, stream>>>(W, Wb, (int)(WN / 4));
    cvt_kernel<<<1024, 256, 0, stream>>>(x, xb, (int)(XN / 4));
  }
  // zero s and bb (contiguous)
  hipMemsetAsync(ws, 0, 2 * (size_t)(1 << 18), stream);

  dim3 grid(NCHUNKS, 4);
  for (int it = 0; it < 3; ++it) {
    if (it) {
      softmax_kernel<<<NC, 256, 0, stream>>>(bb, cmat);
      hipMemsetAsync(ws, 0, (size_t)(1 << 18), stream);  // zero s
    }
    if (fast)
      s_pass_kernel<true><<<grid, 256, 0, stream>>>(x, W, xb, Wb, cmat, s, it == 0 ? 1 : 0);
    else
      s_pass_kernel<false><<<grid, 256, 0, stream>>>(x, W, xb, Wb, cmat, s, it == 0 ? 1 : 0);
    float* vdst = (it == 2) ? out : vbuf;
    squash_kernel<<<256, 256, 0, stream>>>(s, vdst);
    if (it < 2) {
      if (fast)
        a_pass_kernel<true><<<grid, 256, 0, stream>>>(x, W, xb, Wb, vbuf, bb);
      else
        a_pass_kernel<false><<<grid, 256, 0, stream>>>(x, W, xb, Wb, vbuf, bb);
    }
  }
}